// Round 1
// baseline (745.789 us; speedup 1.0000x reference)
//
#include <hip/hip_runtime.h>
#include <cstdint>

#define ALPHA_C 0.15f
#define ONE_MINUS_ALPHA 0.85f
#define CLIP_C 5.0f
#define EPS_C 1e-6f
#define LN_EPS_C 1e-5f

#define Bb 4
#define Ss 4096
#define Dd 2048
#define Mtot (Bb * Ss)  // 16384

typedef __attribute__((ext_vector_type(8))) short bf16x8;
typedef __attribute__((ext_vector_type(4))) float f32x4;

__device__ __forceinline__ short f2bf(float f) {
  union { float f; uint32_t u; } v; v.f = f;
  uint32_t r = v.u + 0x7fffu + ((v.u >> 16) & 1u);  // RNE
  return (short)(r >> 16);
}
__device__ __forceinline__ float sigf(float x) { return 1.0f / (1.0f + __expf(-x)); }
__device__ __forceinline__ float geluf(float x) {
  const float c = 0.7978845608028654f;  // sqrt(2/pi)
  float x3 = x * x * x;
  return 0.5f * x * (1.0f + tanhf(c * (x + 0.044715f * x3)));
}

__device__ __forceinline__ void load_lds16(const short* g, short* l) {
  __builtin_amdgcn_global_load_lds((__attribute__((address_space(1))) void*)g,
                                   (__attribute__((address_space(3))) void*)l, 16, 0, 0);
}

// ================= 256x256 8-wave deep-pipelined GEMM (T2+T3/T4+T5) ==============
// C[M,N] = A[M,K](bf16) @ Bt[N,K](bf16)^T.
// BK=64, 2 LDS buffers (128 KiB), 512 thr = 8 waves (2M x 4N), per-wave 128x64 out.
// K-tile = 4 phases: {ds_read subtile | setprio(1) 16xMFMA setprio(0) | s_barrier}.
// Phase 1 bursts the FULL next-tile prefetch (8 x global_load_lds) then waits
// counted vmcnt(8): the 8 outstanding are the NEXT tile's; current tile's loads
// were issued one full tile (4 phases) earlier -> latency hidden (T4, m218).
// Raw s_barrier (not __syncthreads) so no vmcnt(0) drain in the loop.
// LDS swizzle (T2): chunk' = chunk ^ (row&7) applied on the per-lane GLOBAL source
// (gload_lds dest must stay linear, m104/m173); ds_read XORs the same key ->
// 64 lanes spread evenly over all 8 16B-column slots (bank-optimal for b128).
// Safety: stages for tile t+1 hit buf (t+1)&1 whose reads (tile t-1) completed
// before the preceding barrier; reads of tile t gated by vmcnt(8)+barrier.
// MODE 0: fp32 out = v + bias.
// MODE 3: bx==0 -> score = sig(q)*sig(k) via lane-pair shfl (Q/K cols interleaved);
//         else  -> out1 bf16 = gelu(v+bias), col-256.
#define RD_A(KK)                                                                     \
  _Pragma("unroll") for (int m = 0; m < 8; ++m)                                      \
      a[m] = *(const bf16x8*)&Ab[(wr128 + m * 16 + l16) * 64 +                       \
                                 ((((KK) * 4 + quad) ^ key) * 8)];
#define RD_B(KK)                                                                     \
  _Pragma("unroll") for (int n = 0; n < 4; ++n)                                      \
      bfr[KK][n] = *(const bf16x8*)&Bb2[(wc64 + n * 16 + l16) * 64 +                 \
                                        ((((KK) * 4 + quad) ^ key) * 8)];
#define MFMA_PH(KK, NB)                                                              \
  __builtin_amdgcn_s_setprio(1);                                                     \
  _Pragma("unroll") for (int m = 0; m < 8; ++m) {                                    \
    acc[m][NB] = __builtin_amdgcn_mfma_f32_16x16x32_bf16(a[m], bfr[KK][NB],          \
                                                         acc[m][NB], 0, 0, 0);       \
    acc[m][NB + 1] = __builtin_amdgcn_mfma_f32_16x16x32_bf16(a[m], bfr[KK][NB + 1],  \
                                                             acc[m][NB + 1], 0, 0, 0);\
  }                                                                                  \
  __builtin_amdgcn_s_setprio(0);
#define BARF()                                                                       \
  {                                                                                  \
    asm volatile("" ::: "memory");                                                   \
    __builtin_amdgcn_s_barrier();                                                    \
    asm volatile("" ::: "memory");                                                   \
  }
#define STAGE(tt)                                                                    \
  {                                                                                  \
    short* ls = smem + ((tt) & 1) * 32768;                                           \
    const long co = (long)(tt) * 64;                                                 \
    _Pragma("unroll") for (int i = 0; i < 4; ++i)                                    \
        load_lds16(baseA + (long)i * 64 * lda + co, ls + (i * 64 + w * 8) * 64);     \
    _Pragma("unroll") for (int i = 0; i < 4; ++i)                                    \
        load_lds16(baseB + (long)i * 64 * ldb + co,                                  \
                   ls + 16384 + (i * 64 + w * 8) * 64);                              \
  }

template <int MODE>
__global__ __launch_bounds__(512, 2) void gemm256(
    const short* __restrict__ A, const short* __restrict__ Bt, void* __restrict__ out0,
    void* __restrict__ out1, const float* __restrict__ bias, int K, int lda, int ldb,
    int ldc, int nbx) {
  __shared__ short smem[65536];  // 128 KiB: 2 bufs x (A 32K + B 32K)

  const int tid = threadIdx.x;
  const int w = tid >> 6;
  const int lane = tid & 63;
  const int quad = lane >> 4;
  const int l16 = lane & 15;
  const int key = l16 & 7;
  const int wr = w >> 2;  // 0..1
  const int wc = w & 3;   // 0..3
  const int wr128 = wr * 128;
  const int wc64 = wc * 64;

  // bijective XCD swizzle (grid % 8 == 0): same-XCD blocks sweep bx -> A-slab L2 reuse
  const int nwg = gridDim.x;
  const int swz = (blockIdx.x & 7) * (nwg >> 3) + (blockIdx.x >> 3);
  const int by = swz / nbx;
  const int bx = swz - by * nbx;
  const int m0 = by * 256;
  const int n0 = bx * 256;

  // staging: lane l -> row l>>3 (of 8-row wave group), global chunk (l&7)^(l>>3);
  // LDS dest linear => LDS(row,c) holds global(row, c^(row&7)) (involution).
  const int srow = w * 8 + (lane >> 3);
  const int schunk = (lane & 7) ^ (lane >> 3);
  const short* baseA = A + (long)(m0 + srow) * lda + schunk * 8;
  const short* baseB = Bt + (long)(n0 + srow) * ldb + schunk * 8;

  const int NT = K >> 6;

  f32x4 acc[8][4] = {};
  bf16x8 a[8], bfr[2][4];

  STAGE(0);

  for (int t = 0; t < NT; ++t) {
    const short* Ab = smem + (t & 1) * 32768;
    const short* Bb2 = Ab + 16384;
    // ---- phase 1: prefetch burst + counted wait + quadrant (kk0, n0-1)
    if (t + 1 < NT) {
      STAGE(t + 1);
      asm volatile("s_waitcnt vmcnt(8)" ::: "memory");  // current tile landed
    } else {
      asm volatile("s_waitcnt vmcnt(0)" ::: "memory");
    }
    __builtin_amdgcn_s_barrier();
    asm volatile("" ::: "memory");
    RD_A(0);
    RD_B(0);
    MFMA_PH(0, 0);
    BARF();
    // ---- phase 2: (kk0, n2-3)
    RD_B(1);
    MFMA_PH(0, 2);
    BARF();
    // ---- phase 3: (kk1, n0-1)
    RD_A(1);
    MFMA_PH(1, 0);
    BARF();
    // ---- phase 4: (kk1, n2-3)
    MFMA_PH(1, 2);
    BARF();
  }

#pragma unroll
  for (int m = 0; m < 8; ++m) {
#pragma unroll
    for (int r = 0; r < 4; ++r) {
      const int row = m0 + wr128 + m * 16 + quad * 4 + r;
#pragma unroll
      for (int n = 0; n < 4; ++n) {
        const int col = n0 + wc64 + n * 16 + l16;
        float v = acc[m][n][r] + bias[col];
        if (MODE == 0) {
          ((float*)out0)[(long)row * ldc + col] = v;
        } else {  // MODE 3
          if (n0 == 0) {  // block-uniform score region (Q/K interleaved cols)
            float sh = __shfl_xor(v, 1);
            if (!(lane & 1))
              ((float*)out0)[(long)row * 128 + (col >> 1)] = sigf(v) * sigf(sh);
          } else {
            ((short*)out1)[(long)row * 2048 + (col - 256)] = f2bf(geluf(v));
          }
        }
      }
    }
  }
}

// ---------------- GEMM: C[M,N] = A[M,K](bf16) * Bt[N,K](bf16)^T ----------------
// (old 128x128 template, kept for MODE 4 fused proj+gate and MODE 5 split-K)
#define BM 128
#define BN 128
#define BK 32

template <int MODE>
__global__ __launch_bounds__(256, 4) void gemm_tn(
    const short* __restrict__ A, const short* __restrict__ Bt, void* __restrict__ out0,
    void* __restrict__ out1, const float* __restrict__ bias, int K, int lda, int ldb,
    int ldc, int nbx, long pstride) {
  __shared__ __align__(16) short As[BM * BK];
  __shared__ __align__(16) short Bs[BN * BK];

  const int tid = threadIdx.x;
  const int wave = tid >> 6;
  const int lane = tid & 63;
  const int quad = lane >> 4;
  const int l16 = lane & 15;

  const int bid = blockIdx.x;
  const int panel = bid / (8 * nbx);
  const int rem = bid - panel * (8 * nbx);
  const int by = panel * 8 + (rem & 7);
  const int bx = rem >> 3;
  const int m0 = by * BM;
  const int n0 = bx * BN;
  const int wm = (wave & 1) * 64;
  const int wn = (wave >> 1) * 64;

  if (MODE == 5) {  // split-K offset
    A += (long)blockIdx.y * K;
    Bt += (long)blockIdx.y * K;
  }

  const int srow = wave * 32 + (lane >> 2);
  const int skoff = ((lane & 3) ^ ((lane >> 3) & 3)) * 8;
  const short* agp = A + (long)(m0 + srow) * lda + skoff;
  const short* bgp = Bt + (long)(n0 + srow) * ldb + skoff;
  const short* agp2 = agp + (long)16 * lda;
  const short* bgp2 = bgp + (long)16 * ldb;
  short* al = As + (wave * 32) * BK;
  short* al2 = al + 16 * BK;
  short* bl = Bs + (wave * 32) * BK;
  short* bl2 = bl + 16 * BK;

  const int rsw = (l16 >> 1) & 3;  // read-side swizzle key

  f32x4 acc[4][4] = {};

  for (int k0 = 0; k0 < K; k0 += BK) {
    __syncthreads();
    load_lds16(agp + k0, al);
    load_lds16(agp2 + k0, al2);
    load_lds16(bgp + k0, bl);
    load_lds16(bgp2 + k0, bl2);
    __syncthreads();

    bf16x8 af[4], bfr[4];
#pragma unroll
    for (int i = 0; i < 4; ++i)
      af[i] = *(const bf16x8*)&As[(wm + i * 16 + l16) * BK + (quad ^ rsw) * 8];
#pragma unroll
    for (int j = 0; j < 4; ++j)
      bfr[j] = *(const bf16x8*)&Bs[(wn + j * 16 + l16) * BK + (quad ^ rsw) * 8];
#pragma unroll
    for (int i = 0; i < 4; ++i)
#pragma unroll
      for (int j = 0; j < 4; ++j)
        acc[i][j] = __builtin_amdgcn_mfma_f32_16x16x32_bf16(af[i], bfr[j], acc[i][j], 0, 0, 0);
  }

#pragma unroll
  for (int i = 0; i < 4; ++i) {
#pragma unroll
    for (int r = 0; r < 4; ++r) {
      const int row = m0 + wm + i * 16 + quad * 4 + r;
#pragma unroll
      for (int j = 0; j < 4; ++j) {
        const int col = n0 + wn + j * 16 + l16;
        float v = acc[i][j][r];
        if (MODE != 5) v += bias[col];
        if (MODE == 0) {
          ((float*)out0)[(long)row * ldc + col] = v;
        } else if (MODE == 5) {
          float* o = (float*)out0 + (long)blockIdx.y * pstride;
          o[(long)row * ldc + col] = v;
        } else if (MODE == 3) {
          if (n0 < 256) {
            float sh = __shfl_xor(v, 1);
            if (!(lane & 1))
              ((float*)out0)[(long)row * 128 + (col >> 1)] = sigf(v) * sigf(sh);
          } else {
            ((short*)out1)[(long)row * 2048 + (col - 256)] = f2bf(geluf(v));
          }
        } else if (MODE == 4) {  // proj cols interleaved (a_i, b_i)
          float sh = __shfl_xor(v, 1);
          if (!(lane & 1))
            ((short*)out0)[(long)row * 1024 + (col >> 1)] = f2bf(v * sigf(v) * sh);
        }
      }
    }
  }
}

// ---------------- elementwise / prep ----------------
__global__ __launch_bounds__(256) void cast_x_kernel(const float* __restrict__ in,
                                                     short* __restrict__ out, long n4) {
  long i = (long)blockIdx.x * blockDim.x + threadIdx.x;
  const long stride = (long)gridDim.x * blockDim.x;
  for (; i < n4; i += stride) {
    float4 v = ((const float4*)in)[i];
    short4 o;
    o.x = f2bf(v.x); o.y = f2bf(v.y); o.z = f2bf(v.z); o.w = f2bf(v.w);
    ((short4*)out)[i] = o;
  }
}

// in [R,C] fp32 -> out[maprow(c)][r] bf16 (out row length R)
// MAP 0: c; 1: 2c; 2: 2c+1; 3: c<1024 ? 2c : 2(c-1024)+1
template <int MAP>
__global__ __launch_bounds__(256) void tcast_kernel(const float* __restrict__ in,
                                                    short* __restrict__ out, int R, int C) {
  __shared__ float t[32][33];
  const int c0 = blockIdx.x * 32, r0 = blockIdx.y * 32;
  const int tx = threadIdx.x, ty = threadIdx.y;
#pragma unroll
  for (int i = 0; i < 32; i += 8)
    t[ty + i][tx] = in[(long)(r0 + ty + i) * C + (c0 + tx)];
  __syncthreads();
#pragma unroll
  for (int i = 0; i < 32; i += 8) {
    const int c = c0 + ty + i;
    const int orow = (MAP == 0) ? c
                   : (MAP == 1) ? 2 * c
                   : (MAP == 2) ? 2 * c + 1
                                : (c < 1024 ? 2 * c : 2 * (c - 1024) + 1);
    out[(long)orow * R + (r0 + tx)] = f2bf(t[tx][ty + i]);
  }
}

// merged bias: [0,256): interleaved Q_b/K_b; [256,2304): lo_proj_b
__global__ void pack_bias_kernel(const float* __restrict__ qb, const float* __restrict__ kb,
                                 const float* __restrict__ lob, float* __restrict__ o) {
  int i = blockIdx.x * 256 + threadIdx.x;
  if (i < 256) o[i] = (i & 1) ? kb[i >> 1] : qb[i >> 1];
  else if (i < 2304) o[i] = lob[i - 256];
}
// proj bias interleaved (a_i, b_i)
__global__ void pack_pbias_kernel(const float* __restrict__ pjb, float* __restrict__ o) {
  int i = blockIdx.x * 256 + threadIdx.x;
  o[i] = (i & 1) ? pjb[1024 + (i >> 1)] : pjb[i >> 1];
}

// ---------------- EMA over time (input = score fp32 [Mtot,128]) ----------------
// ema[t]=0.15*s[t]+0.85*ema[t-1]; 0.85^96=1.7e-7 warm-up -> independent segments.
#define SEG 64
#define WARM 96
__global__ __launch_bounds__(128) void ema_kernel(const float* __restrict__ score,
                                                  float* __restrict__ ema) {
  const int f = threadIdx.x;
  const int b = blockIdx.y;
  const int seg = blockIdx.x;
  const int t0 = seg * SEG;
  const int tstart = (t0 >= WARM) ? (t0 - WARM) : 0;
  const int tend = t0 + SEG;
  const float* __restrict__ base = score + (long)b * Ss * 128;
  float* __restrict__ eb = ema + (long)b * Ss * 128;

  float e = base[(long)tstart * 128 + f];
  if (seg == 0) eb[f] = e;

  int t = tstart + 1;
  const int CH = 8;
  const int nch = (tend - t) / CH;
  float cur[CH];
#pragma unroll
  for (int i = 0; i < CH; ++i) cur[i] = ALPHA_C * base[(long)(t + i) * 128 + f];
  for (int c = 0; c < nch; ++c) {
    float nxt[CH] = {};
    if (c + 1 < nch) {
#pragma unroll
      for (int i = 0; i < CH; ++i) nxt[i] = ALPHA_C * base[(long)(t + CH + i) * 128 + f];
    }
#pragma unroll
    for (int i = 0; i < CH; ++i) {
      e = fmaf(ONE_MINUS_ALPHA, e, cur[i]);
      const int tt = t + i;
      if (tt >= t0) eb[(long)tt * 128 + f] = e;
    }
#pragma unroll
    for (int i = 0; i < CH; ++i) cur[i] = nxt[i];
    t += CH;
  }
  for (; t < tend; ++t) {
    e = fmaf(ONE_MINUS_ALPHA, e, ALPHA_C * base[(long)t * 128 + f]);
    if (t >= t0) eb[(long)t * 128 + f] = e;
  }
}

// per row: mean over 128 ema, clip(ema/denom), * (sum of 4 V-partials + bias), -> bf16
__global__ __launch_bounds__(256) void comb_kernel(const float* __restrict__ ema,
                                                   const float* __restrict__ vpart,
                                                   const float* __restrict__ lob,
                                                   short* __restrict__ xcomb) {
  const int wv = threadIdx.x >> 6;
  const int lane = threadIdx.x & 63;
  const long row = (long)blockIdx.x * 4 + wv;
  const float* er = ema + row * 128;
  float e0 = er[lane], e1 = er[lane + 64];
  float s = e0 + e1;
#pragma unroll
  for (int m = 1; m < 64; m <<= 1) s += __shfl_xor(s, m, 64);
  const float denom = fmaxf(s * (1.0f / 128.0f), EPS_C);
  const float inv = 1.0f / denom;
  const float c0 = fminf(fmaxf(e0 * inv, -CLIP_C), CLIP_C);
  const float c1 = fminf(fmaxf(e1 * inv, -CLIP_C), CLIP_C);
  const long PS = (long)Mtot * 128;
  float va = lob[lane], vb = lob[lane + 64];
#pragma unroll
  for (int p = 0; p < 4; ++p) {
    va += vpart[p * PS + row * 128 + lane];
    vb += vpart[p * PS + row * 128 + lane + 64];
  }
  xcomb[row * 128 + lane] = f2bf(c0 * va);
  xcomb[row * 128 + 64 + lane] = f2bf(c1 * vb);
}

// in-place: io = LN(io + x) * gamma + beta, row = 2048
__global__ __launch_bounds__(256) void ln_kernel(float* __restrict__ io,
                                                 const float* __restrict__ x,
                                                 const float* __restrict__ gamma,
                                                 const float* __restrict__ beta) {
  const long row = blockIdx.x;
  const int tid = threadIdx.x;
  const int wv = tid >> 6, lane = tid & 63;
  float* rp = io + row * 2048;
  const float* xp = x + row * 2048;
  float4 v0 = ((const float4*)rp)[tid * 2];
  float4 v1 = ((const float4*)rp)[tid * 2 + 1];
  float4 x0 = ((const float4*)xp)[tid * 2];
  float4 x1 = ((const float4*)xp)[tid * 2 + 1];
  float h[8] = {v0.x + x0.x, v0.y + x0.y, v0.z + x0.z, v0.w + x0.w,
                v1.x + x1.x, v1.y + x1.y, v1.z + x1.z, v1.w + x1.w};
  float sum = 0.f, ss = 0.f;
#pragma unroll
  for (int i = 0; i < 8; ++i) { sum += h[i]; ss += h[i] * h[i]; }
#pragma unroll
  for (int m = 1; m < 64; m <<= 1) {
    sum += __shfl_xor(sum, m, 64);
    ss += __shfl_xor(ss, m, 64);
  }
  __shared__ float rs[4], rq[4];
  if (lane == 0) { rs[wv] = sum; rq[wv] = ss; }
  __syncthreads();
  sum = rs[0] + rs[1] + rs[2] + rs[3];
  ss = rq[0] + rq[1] + rq[2] + rq[3];
  const float mu = sum * (1.0f / 2048.0f);
  const float var = ss * (1.0f / 2048.0f) - mu * mu;
  const float rstd = rsqrtf(var + LN_EPS_C);
  const int c0 = tid * 8;
  float o[8];
#pragma unroll
  for (int i = 0; i < 8; ++i)
    o[i] = (h[i] - mu) * rstd * gamma[c0 + i] + beta[c0 + i];
  ((float4*)rp)[tid * 2]     = make_float4(o[0], o[1], o[2], o[3]);
  ((float4*)rp)[tid * 2 + 1] = make_float4(o[4], o[5], o[6], o[7]);
}

// ---------------- launch ----------------
extern "C" void kernel_launch(void* const* d_in, const int* in_sizes, int n_in,
                              void* d_out, int out_size, void* d_ws, size_t ws_size,
                              hipStream_t stream) {
  const float* x         = (const float*)d_in[0];
  const float* Q_w       = (const float*)d_in[1];
  const float* Q_b       = (const float*)d_in[2];
  const float* K_w       = (const float*)d_in[3];
  const float* K_b       = (const float*)d_in[4];
  const float* lo_proj_w = (const float*)d_in[5];
  const float* lo_proj_b = (const float*)d_in[6];
  const float* lo_p_w    = (const float*)d_in[7];
  const float* lo_p_b    = (const float*)d_in[8];
  const float* proj_w    = (const float*)d_in[9];
  const float* proj_b    = (const float*)d_in[10];
  const float* O_w       = (const float*)d_in[11];
  const float* O_b       = (const float*)d_in[12];
  const float* ln_g      = (const float*)d_in[13];
  const float* ln_b      = (const float*)d_in[14];

  char* ws = (char*)d_ws;
  size_t off = 0;
  auto alloc = [&](size_t bytes) {
    char* p = ws + off;
    off += (bytes + 255) & ~(size_t)255;
    return p;
  };
  short* x16   = (short*)alloc((size_t)Mtot * Dd * 2);      // x bf16 (dead after merged GEMM)
  short* h16   = (short*)alloc((size_t)Mtot * Dd * 2);      // gelu hidden bf16
  float* score = (float*)alloc((size_t)Mtot * 128 * 4);     // sig(q)*sig(k) fp32
  float* emab  = (float*)alloc((size_t)Mtot * 128 * 4);     // ema fp32
  short* xcomb = (short*)alloc((size_t)Mtot * 128 * 2);     // bf16
  short* gated = (short*)alloc((size_t)Mtot * 1024 * 2);    // bf16
  short* wbig  = (short*)alloc((size_t)2304 * 2048 * 2);    // [QK-interleaved;lo_proj]^T bf16
  short* lpt   = (short*)alloc((size_t)128 * 2048 * 2);     // lo_p^T
  short* prjt  = (short*)alloc((size_t)2048 * 128 * 2);     // proj^T, (a,b)-interleaved rows
  short* ot    = (short*)alloc((size_t)2048 * 1024 * 2);    // O^T
  float* biasb = (float*)alloc(2304 * 4);
  float* pbias = (float*)alloc(2048 * 4);
  float* vpart = (float*)x16;        // 4 x [Mtot,128] fp32 partials, aliases dead x16
  float* outf  = (float*)d_out;      // fp32 [16384,2048] out5

  cast_x_kernel<<<8192, 256, 0, stream>>>(x, x16, (long)Mtot * Dd / 4);
  tcast_kernel<1><<<dim3(4, 64), dim3(32, 8), 0, stream>>>(Q_w, wbig, 2048, 128);
  tcast_kernel<2><<<dim3(4, 64), dim3(32, 8), 0, stream>>>(K_w, wbig, 2048, 128);
  tcast_kernel<0><<<dim3(64, 64), dim3(32, 8), 0, stream>>>(lo_proj_w, wbig + 256 * 2048, 2048, 2048);
  tcast_kernel<0><<<dim3(4, 64), dim3(32, 8), 0, stream>>>(lo_p_w, lpt, 2048, 128);
  tcast_kernel<3><<<dim3(64, 4), dim3(32, 8), 0, stream>>>(proj_w, prjt, 128, 2048);
  tcast_kernel<0><<<dim3(64, 32), dim3(32, 8), 0, stream>>>(O_w, ot, 1024, 2048);
  pack_bias_kernel<<<9, 256, 0, stream>>>(Q_b, K_b, lo_proj_b, biasb);
  pack_pbias_kernel<<<8, 256, 0, stream>>>(proj_b, pbias);

  // [score | gelu-hidden] = x @ [QK-ilv | lo_proj] + bias   (N=2304, 256x256 pipeline)
  gemm256<3><<<576, 512, 0, stream>>>(x16, wbig, score, h16, biasb,
                                      2048, 2048, 2048, 0, 9);
  // ema over time (segmented scan)
  ema_kernel<<<dim3(Ss / SEG, 4), 128, 0, stream>>>(score, emab);
  // V partials = h @ lo_p (split-K x4; x16 is dead, vpart aliases it)
  gemm_tn<5><<<dim3(128, 4), 256, 0, stream>>>(h16, lpt, vpart, nullptr, nullptr,
                                               512, 2048, 2048, 128, 1, (long)Mtot * 128);
  // mean/clip * (sum V partials + bias) -> x_comb bf16
  comb_kernel<<<Mtot / 4, 256, 0, stream>>>(emab, vpart, lo_p_b, xcomb);
  // gated = silu(a)*b fused into proj GEMM (interleaved cols)
  gemm_tn<4><<<16 * 128, 256, 0, stream>>>(xcomb, prjt, gated, nullptr, pbias,
                                           128, 128, 128, 1024, 16, 0);
  // out5 = gated @ O + b  (fp32 into d_out, 256x256 pipeline)
  gemm256<0><<<512, 512, 0, stream>>>(gated, ot, outf, nullptr, O_b,
                                      1024, 1024, 1024, 2048, 8);
  // LN(out5 + x) in place
  ln_kernel<<<Mtot, 256, 0, stream>>>(outf, x, ln_g, ln_b);
}

// Round 2
// 721.119 us; speedup vs baseline: 1.0342x; 1.0342x over previous
//
#include <hip/hip_runtime.h>
#include <cstdint>

#define ALPHA_C 0.15f
#define ONE_MINUS_ALPHA 0.85f
#define CLIP_C 5.0f
#define EPS_C 1e-6f
#define LN_EPS_C 1e-5f

#define Bb 4
#define Ss 4096
#define Dd 2048
#define Mtot (Bb * Ss)  // 16384

typedef __attribute__((ext_vector_type(8))) short bf16x8;
typedef __attribute__((ext_vector_type(4))) float f32x4;

__device__ __forceinline__ short f2bf(float f) {
  union { float f; uint32_t u; } v; v.f = f;
  uint32_t r = v.u + 0x7fffu + ((v.u >> 16) & 1u);  // RNE
  return (short)(r >> 16);
}
__device__ __forceinline__ float sigf(float x) { return 1.0f / (1.0f + __expf(-x)); }
__device__ __forceinline__ float geluf(float x) {
  const float c = 0.7978845608028654f;  // sqrt(2/pi)
  float x3 = x * x * x;
  return 0.5f * x * (1.0f + tanhf(c * (x + 0.044715f * x3)));
}

__device__ __forceinline__ void load_lds16(const short* g, short* l) {
  __builtin_amdgcn_global_load_lds((__attribute__((address_space(1))) void*)g,
                                   (__attribute__((address_space(3))) void*)l, 16, 0, 0);
}

// ================= 256x256 8-wave m201-style pipelined GEMM =====================
// C[M,N] = A[M,K](bf16) @ Bt[N,K](bf16)^T.  BK=64, 2 LDS buffers (128 KiB),
// 512 thr = 8 waves (2M x 4N), per-wave 128x64 out.
// 4 phases per K-tile, each phase = {ds_read ONE quadrant's frags (8/4/8/4 b128)
//   | stage ONE half-tile of tile t+1 (2 x global_load_lds) | s_barrier |
//   lgkmcnt(0) | setprio(1) 16xMFMA setprio(0) | s_barrier}.
// Fine per-phase interleave is the T3 lever (m196: coarse burst = -7..-27%).
// ONE counted vmcnt per K-tile, at phase 0 AFTER issuing next half:
//   outstanding = 8 (tile t, issued during t-1's phases) + 2 (new) -> vmcnt(2)
//   drains tile t, keeps new half in flight; barrier makes it cross-wave safe.
// Buffer-write safety: tile t+1's buffer last ds_read in tile t-1; every wave
//   lgkmcnt(0)-drained its reads before passing t-1's last barrier.
// LDS swizzle: global source chunk pre-XORed with row&7, LDS dest linear,
//   ds_read XORs same key (involution) -> measured 0 bank conflicts.
// MODE 0: fp32 out = v + bias.
// MODE 3: bx==0 -> score = sig(q)*sig(k) lane-pair shfl; else gelu bf16, col-256.

#define RD_A(MH, KK)                                                                 \
  _Pragma("unroll") for (int mm = 0; mm < 4; ++mm)                                   \
      a[mm] = *(const bf16x8*)&Ab[(wr128 + ((MH) * 4 + mm) * 16 + l16) * 64 +        \
                                  ((((KK) * 4 + quad) ^ key) * 8)];
#define RD_B(KK)                                                                     \
  _Pragma("unroll") for (int nn = 0; nn < 4; ++nn)                                   \
      bq[nn] = *(const bf16x8*)&Bl[(wc64 + nn * 16 + l16) * 64 +                     \
                                   ((((KK) * 4 + quad) ^ key) * 8)];
#define MFMA_Q(MH)                                                                   \
  __builtin_amdgcn_s_setprio(1);                                                     \
  _Pragma("unroll") for (int mm = 0; mm < 4; ++mm)                                   \
  _Pragma("unroll") for (int nn = 0; nn < 4; ++nn)                                   \
      acc[(MH) * 4 + mm][nn] = __builtin_amdgcn_mfma_f32_16x16x32_bf16(              \
          a[mm], bq[nn], acc[(MH) * 4 + mm][nn], 0, 0, 0);                           \
  __builtin_amdgcn_s_setprio(0);
#define BARF()                                                                       \
  {                                                                                  \
    asm volatile("" ::: "memory");                                                   \
    __builtin_amdgcn_s_barrier();                                                    \
    asm volatile("" ::: "memory");                                                   \
  }
// half-tile stage: 128 rows x 64 cols = 16 KB = 2 loads/thread (8 KB per round)
#define STAGE_HALF_A(TT, H)                                                          \
  {                                                                                  \
    short* ls = smem + ((TT) & 1) * 32768 + (H) * 8192;                              \
    const long co = (long)(TT) * 64;                                                 \
    load_lds16(baseA + ((H) * 128 + 0) * (long)lda + co, ls + w * 512);              \
    load_lds16(baseA + ((H) * 128 + 64) * (long)lda + co, ls + 4096 + w * 512);      \
  }
#define STAGE_HALF_B(TT, H)                                                          \
  {                                                                                  \
    short* ls = smem + ((TT) & 1) * 32768 + 16384 + (H) * 8192;                      \
    const long co = (long)(TT) * 64;                                                 \
    load_lds16(baseB + ((H) * 128 + 0) * (long)ldb + co, ls + w * 512);              \
    load_lds16(baseB + ((H) * 128 + 64) * (long)ldb + co, ls + 4096 + w * 512);      \
  }

#define TILE_BODY(CB, STG, TN)                                                       \
  {                                                                                  \
    const short* Ab = smem + (CB) * 32768;                                           \
    const short* Bl = Ab + 16384;                                                    \
    /* phase 0: gate */                                                              \
    if (STG) {                                                                       \
      STAGE_HALF_A(TN, 0);                                                           \
      asm volatile("s_waitcnt vmcnt(2)" ::: "memory");                               \
    } else {                                                                         \
      asm volatile("s_waitcnt vmcnt(0)" ::: "memory");                               \
    }                                                                                \
    __builtin_amdgcn_s_barrier();                                                    \
    asm volatile("" ::: "memory");                                                   \
    RD_A(0, 0);                                                                      \
    RD_B(0);                                                                         \
    asm volatile("s_waitcnt lgkmcnt(0)" ::: "memory");                               \
    MFMA_Q(0);                                                                       \
    BARF();                                                                          \
    /* phase 1 */                                                                    \
    RD_A(1, 0);                                                                      \
    if (STG) STAGE_HALF_A(TN, 1);                                                    \
    __builtin_amdgcn_s_barrier();                                                    \
    asm volatile("s_waitcnt lgkmcnt(0)" ::: "memory");                               \
    MFMA_Q(1);                                                                       \
    BARF();                                                                          \
    /* phase 2 */                                                                    \
    RD_A(0, 1);                                                                      \
    RD_B(1);                                                                         \
    if (STG) STAGE_HALF_B(TN, 0);                                                    \
    __builtin_amdgcn_s_barrier();                                                    \
    asm volatile("s_waitcnt lgkmcnt(0)" ::: "memory");                               \
    MFMA_Q(0);                                                                       \
    BARF();                                                                          \
    /* phase 3 */                                                                    \
    RD_A(1, 1);                                                                      \
    if (STG) STAGE_HALF_B(TN, 1);                                                    \
    __builtin_amdgcn_s_barrier();                                                    \
    asm volatile("s_waitcnt lgkmcnt(0)" ::: "memory");                               \
    MFMA_Q(1);                                                                       \
    BARF();                                                                          \
  }

template <int MODE>
__global__ __launch_bounds__(512, 2) void gemm256(
    const short* __restrict__ A, const short* __restrict__ Bt, void* __restrict__ out0,
    void* __restrict__ out1, const float* __restrict__ bias, int K, int lda, int ldb,
    int ldc, int nbx) {
  __shared__ short smem[65536];  // 128 KiB: 2 bufs x (A 32K + B 32K)

  const int tid = threadIdx.x;
  const int w = tid >> 6;
  const int lane = tid & 63;
  const int quad = lane >> 4;
  const int l16 = lane & 15;
  const int key = l16 & 7;
  const int wr = w >> 2;  // 0..1
  const int wc = w & 3;   // 0..3
  const int wr128 = wr * 128;
  const int wc64 = wc * 64;

  // bijective XCD swizzle (grid % 8 == 0): same-XCD blocks sweep bx -> A-slab L2 reuse
  const int nwg = gridDim.x;
  const int swz = (blockIdx.x & 7) * (nwg >> 3) + (blockIdx.x >> 3);
  const int by = swz / nbx;
  const int bx = swz - by * nbx;
  const int m0 = by * 256;
  const int n0 = bx * 256;

  // staging addresses: lane l -> row offset l>>3, global chunk (l&7)^(l>>3)
  const int rowoff = lane >> 3;
  const int schunk = ((lane & 7) ^ (lane >> 3)) * 8;
  const short* baseA = A + (long)(m0 + w * 8 + rowoff) * lda + schunk;
  const short* baseB = Bt + (long)(n0 + w * 8 + rowoff) * ldb + schunk;

  const int NT = K >> 6;  // NT even (K multiple of 128)

  f32x4 acc[8][4] = {};
  bf16x8 a[4], bq[4];

  // prologue: stage all 4 halves of tile 0
  STAGE_HALF_A(0, 0);
  STAGE_HALF_A(0, 1);
  STAGE_HALF_B(0, 0);
  STAGE_HALF_B(0, 1);

  int t = 0;
  for (; t < NT - 2; t += 2) {
    TILE_BODY(0, 1, t + 1);
    TILE_BODY(1, 1, t + 2);
  }
  TILE_BODY(0, 1, t + 1);
  TILE_BODY(1, 0, 0);

#pragma unroll
  for (int m = 0; m < 8; ++m) {
#pragma unroll
    for (int r = 0; r < 4; ++r) {
      const int row = m0 + wr128 + m * 16 + quad * 4 + r;
#pragma unroll
      for (int n = 0; n < 4; ++n) {
        const int col = n0 + wc64 + n * 16 + l16;
        float v = acc[m][n][r] + bias[col];
        if (MODE == 0) {
          ((float*)out0)[(long)row * ldc + col] = v;
        } else {  // MODE 3
          if (n0 == 0) {  // block-uniform score region (Q/K interleaved cols)
            float sh = __shfl_xor(v, 1);
            if (!(lane & 1))
              ((float*)out0)[(long)row * 128 + (col >> 1)] = sigf(v) * sigf(sh);
          } else {
            ((short*)out1)[(long)row * 2048 + (col - 256)] = f2bf(geluf(v));
          }
        }
      }
    }
  }
}

// ---------------- GEMM: C[M,N] = A[M,K](bf16) * Bt[N,K](bf16)^T ----------------
// (old 128x128 template, kept for MODE 4 fused proj+gate and MODE 5 split-K)
#define BM 128
#define BN 128
#define BK 32

template <int MODE>
__global__ __launch_bounds__(256, 4) void gemm_tn(
    const short* __restrict__ A, const short* __restrict__ Bt, void* __restrict__ out0,
    void* __restrict__ out1, const float* __restrict__ bias, int K, int lda, int ldb,
    int ldc, int nbx, long pstride) {
  __shared__ __align__(16) short As[BM * BK];
  __shared__ __align__(16) short Bs[BN * BK];

  const int tid = threadIdx.x;
  const int wave = tid >> 6;
  const int lane = tid & 63;
  const int quad = lane >> 4;
  const int l16 = lane & 15;

  const int bid = blockIdx.x;
  const int panel = bid / (8 * nbx);
  const int rem = bid - panel * (8 * nbx);
  const int by = panel * 8 + (rem & 7);
  const int bx = rem >> 3;
  const int m0 = by * BM;
  const int n0 = bx * BN;
  const int wm = (wave & 1) * 64;
  const int wn = (wave >> 1) * 64;

  if (MODE == 5) {  // split-K offset
    A += (long)blockIdx.y * K;
    Bt += (long)blockIdx.y * K;
  }

  const int srow = wave * 32 + (lane >> 2);
  const int skoff = ((lane & 3) ^ ((lane >> 3) & 3)) * 8;
  const short* agp = A + (long)(m0 + srow) * lda + skoff;
  const short* bgp = Bt + (long)(n0 + srow) * ldb + skoff;
  const short* agp2 = agp + (long)16 * lda;
  const short* bgp2 = bgp + (long)16 * ldb;
  short* al = As + (wave * 32) * BK;
  short* al2 = al + 16 * BK;
  short* bl = Bs + (wave * 32) * BK;
  short* bl2 = bl + 16 * BK;

  const int rsw = (l16 >> 1) & 3;  // read-side swizzle key

  f32x4 acc[4][4] = {};

  for (int k0 = 0; k0 < K; k0 += BK) {
    __syncthreads();
    load_lds16(agp + k0, al);
    load_lds16(agp2 + k0, al2);
    load_lds16(bgp + k0, bl);
    load_lds16(bgp2 + k0, bl2);
    __syncthreads();

    bf16x8 af[4], bfr[4];
#pragma unroll
    for (int i = 0; i < 4; ++i)
      af[i] = *(const bf16x8*)&As[(wm + i * 16 + l16) * BK + (quad ^ rsw) * 8];
#pragma unroll
    for (int j = 0; j < 4; ++j)
      bfr[j] = *(const bf16x8*)&Bs[(wn + j * 16 + l16) * BK + (quad ^ rsw) * 8];
#pragma unroll
    for (int i = 0; i < 4; ++i)
#pragma unroll
      for (int j = 0; j < 4; ++j)
        acc[i][j] = __builtin_amdgcn_mfma_f32_16x16x32_bf16(af[i], bfr[j], acc[i][j], 0, 0, 0);
  }

#pragma unroll
  for (int i = 0; i < 4; ++i) {
#pragma unroll
    for (int r = 0; r < 4; ++r) {
      const int row = m0 + wm + i * 16 + quad * 4 + r;
#pragma unroll
      for (int j = 0; j < 4; ++j) {
        const int col = n0 + wn + j * 16 + l16;
        float v = acc[i][j][r];
        if (MODE != 5) v += bias[col];
        if (MODE == 0) {
          ((float*)out0)[(long)row * ldc + col] = v;
        } else if (MODE == 5) {
          float* o = (float*)out0 + (long)blockIdx.y * pstride;
          o[(long)row * ldc + col] = v;
        } else if (MODE == 3) {
          if (n0 < 256) {
            float sh = __shfl_xor(v, 1);
            if (!(lane & 1))
              ((float*)out0)[(long)row * 128 + (col >> 1)] = sigf(v) * sigf(sh);
          } else {
            ((short*)out1)[(long)row * 2048 + (col - 256)] = f2bf(geluf(v));
          }
        } else if (MODE == 4) {  // proj cols interleaved (a_i, b_i)
          float sh = __shfl_xor(v, 1);
          if (!(lane & 1))
            ((short*)out0)[(long)row * 1024 + (col >> 1)] = f2bf(v * sigf(v) * sh);
        }
      }
    }
  }
}

// ---------------- elementwise / prep ----------------
__global__ __launch_bounds__(256) void cast_x_kernel(const float* __restrict__ in,
                                                     short* __restrict__ out, long n4) {
  long i = (long)blockIdx.x * blockDim.x + threadIdx.x;
  const long stride = (long)gridDim.x * blockDim.x;
  for (; i < n4; i += stride) {
    float4 v = ((const float4*)in)[i];
    short4 o;
    o.x = f2bf(v.x); o.y = f2bf(v.y); o.z = f2bf(v.z); o.w = f2bf(v.w);
    ((short4*)out)[i] = o;
  }
}

// in [R,C] fp32 -> out[maprow(c)][r] bf16 (out row length R)
// MAP 0: c; 1: 2c; 2: 2c+1; 3: c<1024 ? 2c : 2(c-1024)+1
template <int MAP>
__global__ __launch_bounds__(256) void tcast_kernel(const float* __restrict__ in,
                                                    short* __restrict__ out, int R, int C) {
  __shared__ float t[32][33];
  const int c0 = blockIdx.x * 32, r0 = blockIdx.y * 32;
  const int tx = threadIdx.x, ty = threadIdx.y;
#pragma unroll
  for (int i = 0; i < 32; i += 8)
    t[ty + i][tx] = in[(long)(r0 + ty + i) * C + (c0 + tx)];
  __syncthreads();
#pragma unroll
  for (int i = 0; i < 32; i += 8) {
    const int c = c0 + ty + i;
    const int orow = (MAP == 0) ? c
                   : (MAP == 1) ? 2 * c
                   : (MAP == 2) ? 2 * c + 1
                                : (c < 1024 ? 2 * c : 2 * (c - 1024) + 1);
    out[(long)orow * R + (r0 + tx)] = f2bf(t[tx][ty + i]);
  }
}

// merged bias: [0,256): interleaved Q_b/K_b; [256,2304): lo_proj_b
__global__ void pack_bias_kernel(const float* __restrict__ qb, const float* __restrict__ kb,
                                 const float* __restrict__ lob, float* __restrict__ o) {
  int i = blockIdx.x * 256 + threadIdx.x;
  if (i < 256) o[i] = (i & 1) ? kb[i >> 1] : qb[i >> 1];
  else if (i < 2304) o[i] = lob[i - 256];
}
// proj bias interleaved (a_i, b_i)
__global__ void pack_pbias_kernel(const float* __restrict__ pjb, float* __restrict__ o) {
  int i = blockIdx.x * 256 + threadIdx.x;
  o[i] = (i & 1) ? pjb[1024 + (i >> 1)] : pjb[i >> 1];
}

// ---------------- EMA over time (input = score fp32 [Mtot,128]) ----------------
// ema[t]=0.15*s[t]+0.85*ema[t-1]; 0.85^96=1.7e-7 warm-up -> independent segments.
#define SEG 64
#define WARM 96
__global__ __launch_bounds__(128) void ema_kernel(const float* __restrict__ score,
                                                  float* __restrict__ ema) {
  const int f = threadIdx.x;
  const int b = blockIdx.y;
  const int seg = blockIdx.x;
  const int t0 = seg * SEG;
  const int tstart = (t0 >= WARM) ? (t0 - WARM) : 0;
  const int tend = t0 + SEG;
  const float* __restrict__ base = score + (long)b * Ss * 128;
  float* __restrict__ eb = ema + (long)b * Ss * 128;

  float e = base[(long)tstart * 128 + f];
  if (seg == 0) eb[f] = e;

  int t = tstart + 1;
  const int CH = 8;
  const int nch = (tend - t) / CH;
  float cur[CH];
#pragma unroll
  for (int i = 0; i < CH; ++i) cur[i] = ALPHA_C * base[(long)(t + i) * 128 + f];
  for (int c = 0; c < nch; ++c) {
    float nxt[CH] = {};
    if (c + 1 < nch) {
#pragma unroll
      for (int i = 0; i < CH; ++i) nxt[i] = ALPHA_C * base[(long)(t + CH + i) * 128 + f];
    }
#pragma unroll
    for (int i = 0; i < CH; ++i) {
      e = fmaf(ONE_MINUS_ALPHA, e, cur[i]);
      const int tt = t + i;
      if (tt >= t0) eb[(long)tt * 128 + f] = e;
    }
#pragma unroll
    for (int i = 0; i < CH; ++i) cur[i] = nxt[i];
    t += CH;
  }
  for (; t < tend; ++t) {
    e = fmaf(ONE_MINUS_ALPHA, e, ALPHA_C * base[(long)t * 128 + f]);
    if (t >= t0) eb[(long)t * 128 + f] = e;
  }
}

// per row: mean over 128 ema, clip(ema/denom), * (sum of 4 V-partials + bias), -> bf16
__global__ __launch_bounds__(256) void comb_kernel(const float* __restrict__ ema,
                                                   const float* __restrict__ vpart,
                                                   const float* __restrict__ lob,
                                                   short* __restrict__ xcomb) {
  const int wv = threadIdx.x >> 6;
  const int lane = threadIdx.x & 63;
  const long row = (long)blockIdx.x * 4 + wv;
  const float* er = ema + row * 128;
  float e0 = er[lane], e1 = er[lane + 64];
  float s = e0 + e1;
#pragma unroll
  for (int m = 1; m < 64; m <<= 1) s += __shfl_xor(s, m, 64);
  const float denom = fmaxf(s * (1.0f / 128.0f), EPS_C);
  const float inv = 1.0f / denom;
  const float c0 = fminf(fmaxf(e0 * inv, -CLIP_C), CLIP_C);
  const float c1 = fminf(fmaxf(e1 * inv, -CLIP_C), CLIP_C);
  const long PS = (long)Mtot * 128;
  float va = lob[lane], vb = lob[lane + 64];
#pragma unroll
  for (int p = 0; p < 4; ++p) {
    va += vpart[p * PS + row * 128 + lane];
    vb += vpart[p * PS + row * 128 + lane + 64];
  }
  xcomb[row * 128 + lane] = f2bf(c0 * va);
  xcomb[row * 128 + 64 + lane] = f2bf(c1 * vb);
}

// in-place: io = LN(io + x) * gamma + beta, row = 2048
__global__ __launch_bounds__(256) void ln_kernel(float* __restrict__ io,
                                                 const float* __restrict__ x,
                                                 const float* __restrict__ gamma,
                                                 const float* __restrict__ beta) {
  const long row = blockIdx.x;
  const int tid = threadIdx.x;
  const int wv = tid >> 6, lane = tid & 63;
  float* rp = io + row * 2048;
  const float* xp = x + row * 2048;
  float4 v0 = ((const float4*)rp)[tid * 2];
  float4 v1 = ((const float4*)rp)[tid * 2 + 1];
  float4 x0 = ((const float4*)xp)[tid * 2];
  float4 x1 = ((const float4*)xp)[tid * 2 + 1];
  float h[8] = {v0.x + x0.x, v0.y + x0.y, v0.z + x0.z, v0.w + x0.w,
                v1.x + x1.x, v1.y + x1.y, v1.z + x1.z, v1.w + x1.w};
  float sum = 0.f, ss = 0.f;
#pragma unroll
  for (int i = 0; i < 8; ++i) { sum += h[i]; ss += h[i] * h[i]; }
#pragma unroll
  for (int m = 1; m < 64; m <<= 1) {
    sum += __shfl_xor(sum, m, 64);
    ss += __shfl_xor(ss, m, 64);
  }
  __shared__ float rs[4], rq[4];
  if (lane == 0) { rs[wv] = sum; rq[wv] = ss; }
  __syncthreads();
  sum = rs[0] + rs[1] + rs[2] + rs[3];
  ss = rq[0] + rq[1] + rq[2] + rq[3];
  const float mu = sum * (1.0f / 2048.0f);
  const float var = ss * (1.0f / 2048.0f) - mu * mu;
  const float rstd = rsqrtf(var + LN_EPS_C);
  const int c0 = tid * 8;
  float o[8];
#pragma unroll
  for (int i = 0; i < 8; ++i)
    o[i] = (h[i] - mu) * rstd * gamma[c0 + i] + beta[c0 + i];
  ((float4*)rp)[tid * 2]     = make_float4(o[0], o[1], o[2], o[3]);
  ((float4*)rp)[tid * 2 + 1] = make_float4(o[4], o[5], o[6], o[7]);
}

// ---------------- launch ----------------
extern "C" void kernel_launch(void* const* d_in, const int* in_sizes, int n_in,
                              void* d_out, int out_size, void* d_ws, size_t ws_size,
                              hipStream_t stream) {
  const float* x         = (const float*)d_in[0];
  const float* Q_w       = (const float*)d_in[1];
  const float* Q_b       = (const float*)d_in[2];
  const float* K_w       = (const float*)d_in[3];
  const float* K_b       = (const float*)d_in[4];
  const float* lo_proj_w = (const float*)d_in[5];
  const float* lo_proj_b = (const float*)d_in[6];
  const float* lo_p_w    = (const float*)d_in[7];
  const float* lo_p_b    = (const float*)d_in[8];
  const float* proj_w    = (const float*)d_in[9];
  const float* proj_b    = (const float*)d_in[10];
  const float* O_w       = (const float*)d_in[11];
  const float* O_b       = (const float*)d_in[12];
  const float* ln_g      = (const float*)d_in[13];
  const float* ln_b      = (const float*)d_in[14];

  char* ws = (char*)d_ws;
  size_t off = 0;
  auto alloc = [&](size_t bytes) {
    char* p = ws + off;
    off += (bytes + 255) & ~(size_t)255;
    return p;
  };
  short* x16   = (short*)alloc((size_t)Mtot * Dd * 2);      // x bf16 (dead after merged GEMM)
  short* h16   = (short*)alloc((size_t)Mtot * Dd * 2);      // gelu hidden bf16
  float* score = (float*)alloc((size_t)Mtot * 128 * 4);     // sig(q)*sig(k) fp32
  float* emab  = (float*)alloc((size_t)Mtot * 128 * 4);     // ema fp32
  short* xcomb = (short*)alloc((size_t)Mtot * 128 * 2);     // bf16
  short* gated = (short*)alloc((size_t)Mtot * 1024 * 2);    // bf16
  short* wbig  = (short*)alloc((size_t)2304 * 2048 * 2);    // [QK-interleaved;lo_proj]^T bf16
  short* lpt   = (short*)alloc((size_t)128 * 2048 * 2);     // lo_p^T
  short* prjt  = (short*)alloc((size_t)2048 * 128 * 2);     // proj^T, (a,b)-interleaved rows
  short* ot    = (short*)alloc((size_t)2048 * 1024 * 2);    // O^T
  float* biasb = (float*)alloc(2304 * 4);
  float* pbias = (float*)alloc(2048 * 4);
  float* vpart = (float*)x16;        // 4 x [Mtot,128] fp32 partials, aliases dead x16
  float* outf  = (float*)d_out;      // fp32 [16384,2048] out5

  cast_x_kernel<<<8192, 256, 0, stream>>>(x, x16, (long)Mtot * Dd / 4);
  tcast_kernel<1><<<dim3(4, 64), dim3(32, 8), 0, stream>>>(Q_w, wbig, 2048, 128);
  tcast_kernel<2><<<dim3(4, 64), dim3(32, 8), 0, stream>>>(K_w, wbig, 2048, 128);
  tcast_kernel<0><<<dim3(64, 64), dim3(32, 8), 0, stream>>>(lo_proj_w, wbig + 256 * 2048, 2048, 2048);
  tcast_kernel<0><<<dim3(4, 64), dim3(32, 8), 0, stream>>>(lo_p_w, lpt, 2048, 128);
  tcast_kernel<3><<<dim3(64, 4), dim3(32, 8), 0, stream>>>(proj_w, prjt, 128, 2048);
  tcast_kernel<0><<<dim3(64, 32), dim3(32, 8), 0, stream>>>(O_w, ot, 1024, 2048);
  pack_bias_kernel<<<9, 256, 0, stream>>>(Q_b, K_b, lo_proj_b, biasb);
  pack_pbias_kernel<<<8, 256, 0, stream>>>(proj_b, pbias);

  // [score | gelu-hidden] = x @ [QK-ilv | lo_proj] + bias   (N=2304, 256x256 pipeline)
  gemm256<3><<<576, 512, 0, stream>>>(x16, wbig, score, h16, biasb,
                                      2048, 2048, 2048, 0, 9);
  // ema over time (segmented scan)
  ema_kernel<<<dim3(Ss / SEG, 4), 128, 0, stream>>>(score, emab);
  // V partials = h @ lo_p (split-K x4; x16 is dead, vpart aliases it)
  gemm_tn<5><<<dim3(128, 4), 256, 0, stream>>>(h16, lpt, vpart, nullptr, nullptr,
                                               512, 2048, 2048, 128, 1, (long)Mtot * 128);
  // mean/clip * (sum V partials + bias) -> x_comb bf16
  comb_kernel<<<Mtot / 4, 256, 0, stream>>>(emab, vpart, lo_p_b, xcomb);
  // gated = silu(a)*b fused into proj GEMM (interleaved cols)
  gemm_tn<4><<<16 * 128, 256, 0, stream>>>(xcomb, prjt, gated, nullptr, pbias,
                                           128, 128, 128, 1024, 16, 0);
  // out5 = gated @ O + b  (fp32 into d_out, 256x256 pipeline)
  gemm256<0><<<512, 512, 0, stream>>>(gated, ot, outf, nullptr, O_b,
                                      1024, 1024, 1024, 2048, 8);
  // LN(out5 + x) in place
  ln_kernel<<<Mtot, 256, 0, stream>>>(outf, x, ln_g, ln_b);
}